// Round 7
// baseline (113.494 us; speedup 1.0000x reference)
//
#include <hip/hip_runtime.h>
#include <math.h>

// out[b,q] = T_q(xmean_b) * inner_sum[b,q]/IN
//   inner_sum[b,q] = c_q * rawsum[b,q],  rawsum = sum_p sin(pi*(q+1)*x[b,p])*W[q,p]
//   (c_q = coeff_q * exp(-0.03 k^2) factors out of the p-sum -> staging is a raw copy,
//    c applied once per lane in the epilogue)
//   xmean_b = (1/D) sum_q tanh(inner_sum[b,q]);  T_q(x)=cos(q*acos(x)), |xmean|<1
// theta input dead (corr == 0). sin in REVOLUTIONS: sin(pi*k*x) = v_sin((k/2)*x).
// wA[p4][l]=W[l][4p4..], wB[p4][l]=W[l+64][..] (zero past row D-1 / col P-1) ->
// lane-contiguous ds_read_b128, no mask VALU in loop. 256 blocks x 1024 thr (R6 shape).

#define IN_DIM 100
#define MAXD   100
#define NP4    (IN_DIM / 4)     // 25
#define WAVES  16
#define BLK    (WAVES * 64)     // 1024 threads
#define ROWS   WAVES            // 1 batch row per wave
#define INV2PI 0.15915494309189535f

__device__ __forceinline__ float fast_tanh(float v) {
    float e = __expf(2.0f * v);
    return 1.0f - 2.0f / (e + 1.0f);
}

// c_q = coeff_q * exp(-0.03 k^2); finite for all q in [0,128)
__device__ __forceinline__ float cq_of(int q) {
    float k = (float)(q + 1);
    float coeff;
    if (q < 15) {
        coeff = 1.0f / k;
    } else {
        float qf = (float)q;
        float S = 1.0f + 0.2f * __logf(qf / 15.0f) * (1.0f - __expf(-0.03f * (qf - 15.0f)));
        coeff = 1.0f / (k * S);
    }
    return coeff * __expf(-0.03f * k * k);
}

__global__ __launch_bounds__(BLK, 8) void kat_kernel(
    const float* __restrict__ x, const float* __restrict__ W,
    const int* __restrict__ dimp, float* __restrict__ out, int B)
{
    const int D = *dimp;
    const int P = (IN_DIM < D) ? IN_DIM : D;

    __shared__ float4 wA[NP4][64];         // W rows 0..63                (25.6 KB)
    __shared__ float4 wB[NP4][64];         // W rows 64..127 (zero >= D)  (25.6 KB)
    __shared__ float  xr[ROWS][IN_DIM];    // 6.4 KB

    const int t = threadIdx.x;
    const int row0 = blockIdx.x * ROWS;

    {   // stage x rows (float4-coalesced)
        const float4* x4 = (const float4*)(x + (size_t)row0 * IN_DIM);
        for (int i = t; i < ROWS * NP4; i += BLK) {
            int r = i / NP4;
            int p = (i - r * NP4) * 4;
            float4 v = (row0 + r < B) ? x4[i] : make_float4(0.f, 0.f, 0.f, 0.f);
            xr[r][p] = v.x; xr[r][p+1] = v.y; xr[r][p+2] = v.z; xr[r][p+3] = v.w;
        }
    }
    // stage raw W transposed (NO math): rows q>=D and cols p>=P zeroed
    for (int idx = t; idx < NP4 * 128; idx += BLK) {
        int p4 = idx >> 7;
        int q  = idx & 127;
        float4 v = make_float4(0.f, 0.f, 0.f, 0.f);
        if (q < MAXD && q < D) {
            float4 wv = ((const float4*)W)[q * (MAXD / 4) + p4];
            int p = 4 * p4;
            v.x = (p     < P) ? wv.x : 0.0f;
            v.y = (p + 1 < P) ? wv.y : 0.0f;
            v.z = (p + 2 < P) ? wv.z : 0.0f;
            v.w = (p + 3 < P) ? wv.w : 0.0f;
        }
        if (q < 64) wA[p4][q]      = v;
        else        wB[p4][q - 64] = v;
    }
    __syncthreads();

    const int w    = t >> 6;
    const int lane = t & 63;
    const int b    = row0 + w;

    const int q0 = lane;
    const int q1 = lane + 64;

    const float f0 = 0.5f * (float)(q0 + 1);  // revolutions: sin(pi*k*x)=sin2pi((k/2)x)
    const float f1 = 0.5f * (float)(q1 + 1);

    const float4* __restrict__ xw4 = (const float4*)&xr[w][0];

    float a0 = 0.0f, a1 = 0.0f;               // raw sums (c applied after)
    for (int p4 = 0; p4 < NP4; ++p4) {
        float4 xv = xw4[p4];            // wave-uniform LDS broadcast (b128)
        float4 c0 = wA[p4][lane];       // lane-contiguous ds_read_b128
        float4 c1 = wB[p4][lane];       // zero rows for q>=D

        a0 = fmaf(__builtin_amdgcn_sinf(f0 * xv.x), c0.x, a0);
        a1 = fmaf(__builtin_amdgcn_sinf(f1 * xv.x), c1.x, a1);
        a0 = fmaf(__builtin_amdgcn_sinf(f0 * xv.y), c0.y, a0);
        a1 = fmaf(__builtin_amdgcn_sinf(f1 * xv.y), c1.y, a1);
        a0 = fmaf(__builtin_amdgcn_sinf(f0 * xv.z), c0.z, a0);
        a1 = fmaf(__builtin_amdgcn_sinf(f1 * xv.z), c1.z, a1);
        a0 = fmaf(__builtin_amdgcn_sinf(f0 * xv.w), c0.w, a0);
        a1 = fmaf(__builtin_amdgcn_sinf(f1 * xv.w), c1.w, a1);
    }

    // apply per-q constant after the p-sum
    a0 *= cq_of(q0);
    a1 *= cq_of(q1);                    // q1>=D: a1 == c*0 == 0

    float s = fast_tanh(a0) + fast_tanh(a1);  // tanh(0)=0 for q>=D
    #pragma unroll
    for (int m = 32; m; m >>= 1) s += __shfl_xor(s, m);

    const float thr = acosf(s / (float)D) * INV2PI;
    const float inv = 1.0f / (float)IN_DIM;
    if (b < B) {
        if (q0 < D) out[b * D + q0] = __builtin_amdgcn_cosf((float)q0 * thr) * a0 * inv;
        if (q1 < D) out[b * D + q1] = __builtin_amdgcn_cosf((float)q1 * thr) * a1 * inv;
    }
}

extern "C" void kernel_launch(void* const* d_in, const int* in_sizes, int n_in,
                              void* d_out, int out_size, void* d_ws, size_t ws_size,
                              hipStream_t stream) {
    const float* x    = (const float*)d_in[0];
    const float* W    = (const float*)d_in[1];
    // d_in[2] = theta (unused: corr == 0)
    const int*   dimp = (const int*)d_in[3];
    float*       out  = (float*)d_out;

    const int B = in_sizes[0] / IN_DIM;          // 4096
    const int grid = (B + ROWS - 1) / ROWS;      // 256 blocks x 1024 threads

    hipLaunchKernelGGL(kat_kernel, dim3(grid), dim3(BLK), 0, stream,
                       x, W, dimp, out, B);
}

// Round 8
// 15.017 us; speedup vs baseline: 7.5577x; 7.5577x over previous
//
#include <hip/hip_runtime.h>
#include <math.h>

// out[b,q] = T_q(xmean_b) * inner_sum[b,q]/IN
//   inner_sum[b,q] = sum_p c_q*sin(pi*(q+1)*x[b,p])*W[q,p]
//   xmean_b = (1/D) sum_q tanh(inner_sum[b,q]);  T_q(x)=cos(q*acos(x)), |xmean|<1
// theta input dead (corr == 0). sin in REVOLUTIONS: sin(pi*k*x) = v_sin((k/2)*x).
//
// R8: R6 structure (cq folded into staging -- the epilogue-cq variant triggered a
// 32-VGPR allocation + per-iteration scratch spill, 400 MB HBM traffic, 113 us).
// Changes vs R6:
//  - no min-waves launch bound (grid=256 -> only 16 waves/CU exist; the (,8) bound
//    couldn't raise occupancy, only constrain the allocator toward spills)
//  - x read directly from global via readfirstlane-scalarized row pointer ->
//    s_load on the SMEM pipe; removes 400 of 1600 per-CU ds_read_b128 (LDS-issue
//    is the modeled bottleneck at ~8 us/CU)

#define IN_DIM 100
#define MAXD   100
#define NP4    (IN_DIM / 4)     // 25
#define WAVES  16
#define BLK    (WAVES * 64)     // 1024 threads
#define ROWS   WAVES            // 1 batch row per wave
#define INV2PI 0.15915494309189535f

__device__ __forceinline__ float fast_tanh(float v) {
    float e = __expf(2.0f * v);
    return 1.0f - 2.0f / (e + 1.0f);
}

__global__ __launch_bounds__(BLK) void kat_kernel(
    const float* __restrict__ x, const float* __restrict__ W,
    const int* __restrict__ dimp, float* __restrict__ out, int B)
{
    const int D = *dimp;
    const int P = (IN_DIM < D) ? IN_DIM : D;

    __shared__ float4 cwA[NP4][64];        // cq*W rows 0..63               (25.6 KB)
    __shared__ float4 cwB[NP4][64];        // cq*W rows 64..127 (zero >= D) (25.6 KB)

    const int t = threadIdx.x;
    const int row0 = blockIdx.x * ROWS;

    // stage cwA/cwB = cq[q]*W[q][4p4..4p4+3]; q>=D or p>=P -> 0  (R6-proven)
    for (int idx = t; idx < NP4 * 128; idx += BLK) {
        int p4 = idx >> 7;
        int q  = idx & 127;
        float4 v = make_float4(0.f, 0.f, 0.f, 0.f);
        if (q < MAXD && q < D) {
            float k = (float)(q + 1);
            float c;
            if (q < 15) {
                c = 1.0f / k;
            } else {
                float qf = (float)q;
                float S = 1.0f + 0.2f * __logf(qf / 15.0f) * (1.0f - __expf(-0.03f * (qf - 15.0f)));
                c = 1.0f / (k * S);
            }
            c *= __expf(-0.03f * k * k);
            float4 wv = ((const float4*)W)[q * (MAXD / 4) + p4];
            int p = 4 * p4;
            v.x = (p     < P) ? c * wv.x : 0.0f;
            v.y = (p + 1 < P) ? c * wv.y : 0.0f;
            v.z = (p + 2 < P) ? c * wv.z : 0.0f;
            v.w = (p + 3 < P) ? c * wv.w : 0.0f;
        }
        if (q < 64) cwA[p4][q]      = v;
        else        cwB[p4][q - 64] = v;
    }
    __syncthreads();

    const int w    = t >> 6;
    const int lane = t & 63;
    const int b    = row0 + w;

    // scalarize the (wave-uniform) row base so x loads hit the SMEM pipe
    const int bu = __builtin_amdgcn_readfirstlane((b < B) ? b : (B - 1));
    const float4* __restrict__ xb4 = (const float4*)(x + (size_t)bu * IN_DIM);

    const int q0 = lane;
    const int q1 = lane + 64;

    const float f0 = 0.5f * (float)(q0 + 1);  // revolutions: sin(pi*k*x)=sin2pi((k/2)x)
    const float f1 = 0.5f * (float)(q1 + 1);

    float a0 = 0.0f, a1 = 0.0f;
    for (int p4 = 0; p4 < NP4; ++p4) {
        float4 xv = xb4[p4];            // wave-uniform -> s_load (scalar broadcast)
        float4 c0 = cwA[p4][lane];      // lane-contiguous ds_read_b128
        float4 c1 = cwB[p4][lane];      // zero rows for q>=D

        a0 = fmaf(__builtin_amdgcn_sinf(f0 * xv.x), c0.x, a0);
        a1 = fmaf(__builtin_amdgcn_sinf(f1 * xv.x), c1.x, a1);
        a0 = fmaf(__builtin_amdgcn_sinf(f0 * xv.y), c0.y, a0);
        a1 = fmaf(__builtin_amdgcn_sinf(f1 * xv.y), c1.y, a1);
        a0 = fmaf(__builtin_amdgcn_sinf(f0 * xv.z), c0.z, a0);
        a1 = fmaf(__builtin_amdgcn_sinf(f1 * xv.z), c1.z, a1);
        a0 = fmaf(__builtin_amdgcn_sinf(f0 * xv.w), c0.w, a0);
        a1 = fmaf(__builtin_amdgcn_sinf(f1 * xv.w), c1.w, a1);
    }

    // q>=D contributions staged as zero; tanh(0)=0
    float s = fast_tanh(a0) + fast_tanh(a1);
    #pragma unroll
    for (int m = 32; m; m >>= 1) s += __shfl_xor(s, m);

    const float thr = acosf(s / (float)D) * INV2PI;
    const float inv = 1.0f / (float)IN_DIM;
    if (b < B) {
        if (q0 < D) out[b * D + q0] = __builtin_amdgcn_cosf((float)q0 * thr) * a0 * inv;
        if (q1 < D) out[b * D + q1] = __builtin_amdgcn_cosf((float)q1 * thr) * a1 * inv;
    }
}

extern "C" void kernel_launch(void* const* d_in, const int* in_sizes, int n_in,
                              void* d_out, int out_size, void* d_ws, size_t ws_size,
                              hipStream_t stream) {
    const float* x    = (const float*)d_in[0];
    const float* W    = (const float*)d_in[1];
    // d_in[2] = theta (unused: corr == 0)
    const int*   dimp = (const int*)d_in[3];
    float*       out  = (float*)d_out;

    const int B = in_sizes[0] / IN_DIM;          // 4096
    const int grid = (B + ROWS - 1) / ROWS;      // 256 blocks x 1024 threads = 1/CU

    hipLaunchKernelGGL(kat_kernel, dim3(grid), dim3(BLK), 0, stream,
                       x, W, dimp, out, B);
}